// Round 12
// baseline (63.769 us; speedup 1.0000x reference)
//
#include <hip/hip_runtime.h>

constexpr int kN = 4, kC = 19, kH = 512, kW = 512;
constexpr int kHW = kH * kW;
constexpr int kS = 2048;      // NUM_SUPERPIXEL
constexpr int kSsm = 8192;    // NUM_SMALL
constexpr float kEps = 1e-8f;

constexpr int kNSC = kN * kS * kC;                 // need_mark domain (155,648)
constexpr int kQuadBlocks = kN * kHW / 4 / 256;    // 1024 (4 pixels/thread)

// ---- workspace layout (bytes) ----
constexpr size_t OFF_AMAX = 0;                                   // u64[N*S*C] (value_bits<<32)|~pix
constexpr size_t SZ_AMAX  = (size_t)kN * kS * kC * 8;
constexpr size_t OFF_MULT = OFF_AMAX + SZ_AMAX;                  // u32[N*Ssm*C] multiplicity
constexpr size_t SZ_MULT  = (size_t)kN * kSsm * kC * 4;
constexpr size_t OFF_NM   = OFF_MULT + SZ_MULT;                  // u32[N*Ssm] needed-channel bits
constexpr size_t SZ_NM    = (size_t)kN * kSsm * 4;
constexpr size_t ZERO_BYTES = OFF_NM + SZ_NM;                    // zeroed region (16B-multiple)
constexpr size_t ZERO_CHUNKS = ZERO_BYTES / 16;
constexpr size_t OFF_TM   = ZERO_BYTES;                          // u32[N*S] target channel bitmask
constexpr size_t SZ_TM    = (size_t)kN * kS * 4;
constexpr size_t OFF_PL   = OFF_TM + SZ_TM;                      // f32[kQuadBlocks] loss partials
constexpr size_t SZ_PL    = (size_t)kQuadBlocks * 4;
constexpr size_t OFF_PN   = OFF_PL + SZ_PL;                      // i32[kQuadBlocks] nv partials
constexpr size_t SZ_PN    = (size_t)kQuadBlocks * 4;
constexpr size_t WS_TOTAL = OFF_PN + SZ_PN;

// Fused: zero the accumulator region + build tmask.
__global__ void init_kernel(const float* __restrict__ targets,
                            unsigned* __restrict__ tmask,
                            ulong2* __restrict__ ws) {
    size_t gid = (size_t)blockIdx.x * blockDim.x + threadIdx.x;
    if (gid < ZERO_CHUNKS) ws[gid] = ulong2{0ULL, 0ULL};
    if (gid < (size_t)kN * kS) {
        const float* t = targets + gid * (kC + 1);
        unsigned m = 0;
#pragma unroll
        for (int c = 0; c < kC; ++c)
            if (t[c] > 0.f) m |= (1u << c);
        tmask[gid] = m;
    }
}

// Weak branch, 4 pixels/thread with float4 channel loads.
// R11: R9's two-pass (sum-only, no x[19] array) made quad-threads cheap:
// only 4 running sums live => ~30 VGPR (R4's 2-pixel failure was the x[19]
// register bloat). 4x fewer load instructions, 16B/lane coalescing, 4x
// outstanding bytes/wave. Dead pixels in a live quad cost extra __expf
// (VALU is at 19% — free) and no extra HBM (shared cache lines).
__global__ void weak_argmax_kernel(const float* __restrict__ logits,
                                   const unsigned char* __restrict__ mask,
                                   const int* __restrict__ seg,
                                   const unsigned* __restrict__ tmask,
                                   unsigned long long* __restrict__ amax) {
    int t = blockIdx.x * blockDim.x + threadIdx.x;
    int n = t / (kHW / 4);
    int p = (t - n * (kHW / 4)) * 4;
    int pixbase = n * kHW + p;

    uchar4 mk = *(const uchar4*)&mask[pixbase];
    int4 sg = *(const int4*)&seg[pixbase];
    const unsigned* tmn = tmask + n * kS;
    unsigned tm0 = mk.x ? tmn[sg.x] : 0u;
    unsigned tm1 = mk.y ? tmn[sg.y] : 0u;
    unsigned tm2 = mk.z ? tmn[sg.z] : 0u;
    unsigned tm3 = mk.w ? tmn[sg.w] : 0u;
    if (!(tm0 | tm1 | tm2 | tm3)) return;

    const float* base = logits + (size_t)n * kC * kHW + p;
    float s0 = 0.f, s1 = 0.f, s2 = 0.f, s3 = 0.f;
#pragma unroll
    for (int c = 0; c < kC; ++c) {
        float4 x = *(const float4*)&base[(size_t)c * kHW];
        s0 += __expf(x.x);
        s1 += __expf(x.y);
        s2 += __expf(x.z);
        s3 += __expf(x.w);
    }

    unsigned long long* an = amax + (size_t)n * kS * kC;
#define WEAK_PIX(I, TM, SG, SUM)                                               \
    if (TM) {                                                                  \
        float inv = 1.f / (SUM);                                               \
        unsigned long long lowbits = (unsigned)(~(unsigned)(p + I));           \
        unsigned long long* dst = an + (size_t)(SG)*kC;                        \
        unsigned bits = TM;                                                    \
        while (bits) {                                                         \
            int c = __ffs(bits) - 1;                                           \
            bits &= bits - 1;                                                  \
            float v = __expf(base[(size_t)c * kHW + I]) * inv;                 \
            unsigned long long key =                                           \
                ((unsigned long long)__float_as_uint(v) << 32) | lowbits;      \
            atomicMax(&dst[c], key);                                           \
        }                                                                      \
    }
    WEAK_PIX(0, tm0, sg.x, s0)
    WEAK_PIX(1, tm1, sg.y, s1)
    WEAK_PIX(2, tm2, sg.z, s2)
    WEAK_PIX(3, tm3, sg.w, s3)
#undef WEAK_PIX
}

// For each live (n,s,c) pair: record needed-channel bit and multiplicity.
// (R10 summation-order swap: mult lets strong emit the final loss directly.)
__global__ void need_mark_kernel(const unsigned long long* __restrict__ amax,
                                 const unsigned* __restrict__ tmask,
                                 const int* __restrict__ small_w,
                                 unsigned* __restrict__ needmask,
                                 unsigned* __restrict__ mult) {
    int gid = blockIdx.x * blockDim.x + threadIdx.x;
    if (gid >= kNSC) return;
    int n = gid / (kS * kC);
    int rem = gid - n * (kS * kC);
    int s = rem / kC;
    int c = rem - s * kC;
    if (!((tmask[n * kS + s] >> c) & 1u)) return;
    unsigned long long packed = amax[gid];
    if (packed == 0ULL) return;  // empty segment (has_pixel == false)
    unsigned pix = ~(unsigned)(packed & 0xFFFFFFFFULL);
    int sel = small_w[(size_t)n * kHW + pix];
    atomicOr(&needmask[n * kSsm + sel], 1u << c);
    atomicAdd(&mult[((size_t)n * kSsm + sel) * kC + c], 1u);
}

// Strong branch, 4 pixels/thread, fused final gather: mult-weighted nll
// accumulated thread-locally, block-reduced to one (loss, nv) partial.
__global__ void strong_loss_kernel(const float* __restrict__ logits,
                                   const unsigned char* __restrict__ mask,
                                   const int* __restrict__ seg,
                                   const unsigned* __restrict__ needmask,
                                   const unsigned* __restrict__ mult,
                                   float* __restrict__ ploss,
                                   int* __restrict__ pnv) {
    __shared__ float sLoss[4];
    __shared__ int sNv[4];
    int t = blockIdx.x * blockDim.x + threadIdx.x;
    int n = t / (kHW / 4);
    int p = (t - n * (kHW / 4)) * 4;
    int pixbase = n * kHW + p;

    uchar4 mk = *(const uchar4*)&mask[pixbase];
    int4 sg = *(const int4*)&seg[pixbase];
    const unsigned* nmn = needmask + n * kSsm;
    unsigned nm0 = mk.x ? nmn[sg.x] : 0u;
    unsigned nm1 = mk.y ? nmn[sg.y] : 0u;
    unsigned nm2 = mk.z ? nmn[sg.z] : 0u;
    unsigned nm3 = mk.w ? nmn[sg.w] : 0u;

    float loss = 0.f;
    int nvv = 0;
    if (nm0 | nm1 | nm2 | nm3) {
        const float* base = logits + (size_t)n * kC * kHW + p;
        float s0 = 0.f, s1 = 0.f, s2 = 0.f, s3 = 0.f;
#pragma unroll
        for (int c = 0; c < kC; ++c) {
            float4 x = *(const float4*)&base[(size_t)c * kHW];
            s0 += __expf(x.x);
            s1 += __expf(x.y);
            s2 += __expf(x.z);
            s3 += __expf(x.w);
        }
        const unsigned* mn = mult + (size_t)n * kSsm * kC;
#define STRONG_PIX(I, NM, SG, SUM)                                             \
    if (NM) {                                                                  \
        float inv = 1.f / (SUM);                                               \
        const unsigned* row = mn + (size_t)(SG)*kC;                            \
        unsigned bits = NM;                                                    \
        while (bits) {                                                         \
            int c = __ffs(bits) - 1;                                           \
            bits &= bits - 1;                                                  \
            unsigned m = row[c];                                               \
            float v = __expf(base[(size_t)c * kHW + I]) * inv;                 \
            loss += (float)m * (-__logf(v + kEps));                            \
            nvv += (int)m;                                                     \
        }                                                                      \
    }
        STRONG_PIX(0, nm0, sg.x, s0)
        STRONG_PIX(1, nm1, sg.y, s1)
        STRONG_PIX(2, nm2, sg.z, s2)
        STRONG_PIX(3, nm3, sg.w, s3)
#undef STRONG_PIX
    }
    // all threads reach here — block reduction
#pragma unroll
    for (int off = 32; off > 0; off >>= 1) {
        loss += __shfl_down(loss, off);
        nvv += __shfl_down(nvv, off);
    }
    int wave = threadIdx.x >> 6;
    if ((threadIdx.x & 63) == 0) {
        sLoss[wave] = loss;
        sNv[wave] = nvv;
    }
    __syncthreads();
    if (threadIdx.x == 0) {
        ploss[blockIdx.x] = sLoss[0] + sLoss[1] + sLoss[2] + sLoss[3];
        pnv[blockIdx.x]   = sNv[0] + sNv[1] + sNv[2] + sNv[3];
    }
}

// Single-block reduction of the 1024 per-block partials + final divide.
__global__ void finalize_kernel(const float* __restrict__ ploss,
                                const int* __restrict__ pnv,
                                float* __restrict__ out) {
    __shared__ float sLoss[4];
    __shared__ int sNv[4];
    float lv = 0.f;
    int nvv = 0;
    for (int i = threadIdx.x; i < kQuadBlocks; i += 256) {
        lv += ploss[i];
        nvv += pnv[i];
    }
#pragma unroll
    for (int off = 32; off > 0; off >>= 1) {
        lv += __shfl_down(lv, off);
        nvv += __shfl_down(nvv, off);
    }
    int wave = threadIdx.x >> 6;
    if ((threadIdx.x & 63) == 0) {
        sLoss[wave] = lv;
        sNv[wave] = nvv;
    }
    __syncthreads();
    if (threadIdx.x == 0) {
        float tl = sLoss[0] + sLoss[1] + sLoss[2] + sLoss[3];
        int tn = sNv[0] + sNv[1] + sNv[2] + sNv[3];
        out[0] = tl / (float)(1 + tn);
    }
}

extern "C" void kernel_launch(void* const* d_in, const int* in_sizes, int n_in,
                              void* d_out, int out_size, void* d_ws, size_t ws_size,
                              hipStream_t stream) {
    const float* inputs            = (const float*)d_in[0];
    const float* inputs_weak       = (const float*)d_in[1];
    const float* targets           = (const float*)d_in[2];
    const unsigned char* spmasks      = (const unsigned char*)d_in[3];
    const unsigned char* spmasks_weak = (const unsigned char*)d_in[4];
    // d_in[5] superpixels: unused by the reference
    const int* superpixels_weak    = (const int*)d_in[6];
    const int* superpixel_smalls   = (const int*)d_in[7];
    const int* spx_smalls_weak     = (const int*)d_in[8];
    float* out = (float*)d_out;

    unsigned long long* amax = (unsigned long long*)((char*)d_ws + OFF_AMAX);
    unsigned* mult           = (unsigned*)((char*)d_ws + OFF_MULT);
    unsigned* needmask       = (unsigned*)((char*)d_ws + OFF_NM);
    unsigned* tmask          = (unsigned*)((char*)d_ws + OFF_TM);
    float* ploss             = (float*)((char*)d_ws + OFF_PL);
    int* pnv                 = (int*)((char*)d_ws + OFF_PN);

    int initThreads = (int)ZERO_CHUNKS;
    init_kernel<<<(initThreads + 255) / 256, 256, 0, stream>>>(targets, tmask,
                                                               (ulong2*)d_ws);
    weak_argmax_kernel<<<kQuadBlocks, 256, 0, stream>>>(inputs_weak, spmasks_weak,
                                                        superpixels_weak, tmask, amax);
    need_mark_kernel<<<(kNSC + 255) / 256, 256, 0, stream>>>(amax, tmask,
                                                             spx_smalls_weak,
                                                             needmask, mult);
    strong_loss_kernel<<<kQuadBlocks, 256, 0, stream>>>(inputs, spmasks,
                                                        superpixel_smalls,
                                                        needmask, mult, ploss, pnv);
    finalize_kernel<<<1, 256, 0, stream>>>(ploss, pnv, out);
}